// Round 2
// baseline (648.485 us; speedup 1.0000x reference)
//
#include <hip/hip_runtime.h>
#include <hip/hip_bf16.h>
#include <stdint.h>
#include <stddef.h>

// LoRALinear: M=B*S=8192, K=IN_F=4096, N=OUT_F=4096, RANK=16, SCALING=2
// All d_in / d_out buffers are FLOAT32 (per reference). Compute via bf16 MFMA.
#define M_TOT 8192
#define K_TOT 4096
#define N_TOT 4096
#define RANK  16
#define SCALING 2.0f

typedef short bf16x8 __attribute__((ext_vector_type(8)));   // 8 bf16 = 4 VGPRs
typedef float f32x4  __attribute__((ext_vector_type(4)));

#define MFMA_16x16x32(a, b, c) __builtin_amdgcn_mfma_f32_16x16x32_bf16((a), (b), (c), 0, 0, 0)

__device__ __forceinline__ void async_copy16(void* lds, const void* g) {
    __builtin_amdgcn_global_load_lds(
        (const __attribute__((address_space(1))) uint32_t*)g,
        (__attribute__((address_space(3))) uint32_t*)lds,
        16, 0, 0);
}

// ---------------------------------------------------------------------------
// fp32 -> bf16 conversion, 8 elems/thread (float4 x2 in, 16B out)
// ---------------------------------------------------------------------------
__global__ __launch_bounds__(256) void cvt_f32_to_bf16(
    const float* __restrict__ src, __hip_bfloat16* __restrict__ dst, int n)
{
    int i = (blockIdx.x * 256 + threadIdx.x) * 8;
    if (i >= n) return;
    float4 a = *(const float4*)(src + i);
    float4 b = *(const float4*)(src + i + 4);
    union { bf16x8 v; __hip_bfloat16 h[8]; } u;
    u.h[0] = __float2bfloat16(a.x); u.h[1] = __float2bfloat16(a.y);
    u.h[2] = __float2bfloat16(a.z); u.h[3] = __float2bfloat16(a.w);
    u.h[4] = __float2bfloat16(b.x); u.h[5] = __float2bfloat16(b.y);
    u.h[6] = __float2bfloat16(b.z); u.h[7] = __float2bfloat16(b.w);
    *(bf16x8*)(dst + i) = u.v;
}

// ---------------------------------------------------------------------------
// T[m][r] = SCALING * sum_k X[m][k]*loraA[r][k]  (bf16 in/out, T: [M][16])
// ---------------------------------------------------------------------------
__global__ __launch_bounds__(256) void lora_t_kernel(
    const __hip_bfloat16* __restrict__ X,      // [M][K] bf16 (ws)
    const __hip_bfloat16* __restrict__ loraA,  // [RANK][K] bf16 (ws)
    __hip_bfloat16* __restrict__ T)            // [M][RANK] bf16 (ws)
{
    const int lane = threadIdx.x & 63;
    const int wid  = threadIdx.x >> 6;
    const int m0   = (blockIdx.x * 4 + wid) * 16;
    const int lrow = lane & 15;
    const int lk   = lane >> 4;

    f32x4 acc = {};
    const __hip_bfloat16* xp = X + (size_t)(m0 + lrow) * K_TOT + lk * 8;
    const __hip_bfloat16* ap = loraA + (size_t)lrow * K_TOT + lk * 8;

#pragma unroll 4
    for (int k0 = 0; k0 < K_TOT; k0 += 32) {
        bf16x8 av = *(const bf16x8*)xp;
        bf16x8 bv = *(const bf16x8*)ap;
        xp += 32; ap += 32;
        acc = MFMA_16x16x32(av, bv, acc);
    }
#pragma unroll
    for (int r = 0; r < 4; r++) {
        int gm = m0 + lk * 4 + r;
        T[(size_t)gm * RANK + lrow] = __float2bfloat16(SCALING * acc[r]);
    }
}

// ---------------------------------------------------------------------------
// Main GEMM: out[m][n] = (sum_k X[m][k]*W[n][k])*scale[n] + sum_r T[m][r]*loraB[n][r]
// 128x128 tile, BK=32, 4 waves x 4x4 16x16x32 MFMA frags, global_load_lds(16B).
// ---------------------------------------------------------------------------
#define BM 128
#define BN 128
#define BK 32

__global__ __launch_bounds__(256) void gemm_lora_kernel(
    const __hip_bfloat16* __restrict__ X,      // [M][K] bf16 (ws)
    const __hip_bfloat16* __restrict__ W,      // [N][K] bf16 (ws)
    const float* __restrict__ scale,           // [N] f32
    const __hip_bfloat16* __restrict__ loraB,  // [N][RANK] bf16 (ws)
    const __hip_bfloat16* __restrict__ T,      // [M][RANK] bf16 (ws, pre-scaled)
    float* __restrict__ out)                   // [M][N] f32
{
    __shared__ __align__(16) __hip_bfloat16 As[BM * BK];
    __shared__ __align__(16) __hip_bfloat16 Bs[BN * BK];

    const int tid  = threadIdx.x;
    const int lane = tid & 63;
    const int wid  = tid >> 6;
    const int wm   = (wid & 1) * 64;
    const int wn   = (wid >> 1) * 64;
    const int bm   = blockIdx.x * BM;
    const int bn   = blockIdx.y * BN;

    const int lrow = lane & 15;
    const int lk   = lane >> 4;

    f32x4 acc[4][4] = {};

    const int s0 = tid, s1 = tid + 256;
    const int ar0 = s0 >> 2, ac0 = s0 & 3;
    const int ar1 = s1 >> 2, ac1 = s1 & 3;

    const __hip_bfloat16* xg0 = X + (size_t)(bm + ar0) * K_TOT + ac0 * 8;
    const __hip_bfloat16* xg1 = X + (size_t)(bm + ar1) * K_TOT + ac1 * 8;
    const __hip_bfloat16* wg0 = W + (size_t)(bn + ar0) * K_TOT + ac0 * 8;
    const __hip_bfloat16* wg1 = W + (size_t)(bn + ar1) * K_TOT + ac1 * 8;

    for (int k0 = 0; k0 < K_TOT; k0 += BK) {
        async_copy16(As + s0 * 8, xg0);
        async_copy16(As + s1 * 8, xg1);
        async_copy16(Bs + s0 * 8, wg0);
        async_copy16(Bs + s1 * 8, wg1);
        xg0 += BK; xg1 += BK; wg0 += BK; wg1 += BK;
        __syncthreads();

        bf16x8 af[4], bfr[4];
#pragma unroll
        for (int i = 0; i < 4; i++) {
            af[i]  = *(const bf16x8*)(As + (wm + i * 16 + lrow) * BK + lk * 8);
            bfr[i] = *(const bf16x8*)(Bs + (wn + i * 16 + lrow) * BK + lk * 8);
        }
#pragma unroll
        for (int i = 0; i < 4; i++)
#pragma unroll
            for (int j = 0; j < 4; j++)
                acc[i][j] = MFMA_16x16x32(af[i], bfr[j], acc[i][j]);
        __syncthreads();
    }

    // epilogue: per-output-channel scale on the base term
    float scl[4];
#pragma unroll
    for (int j = 0; j < 4; j++)
        scl[j] = scale[bn + wn + j * 16 + lrow];
#pragma unroll
    for (int i = 0; i < 4; i++)
#pragma unroll
        for (int j = 0; j < 4; j++)
#pragma unroll
            for (int r = 0; r < 4; r++)
                acc[i][j][r] *= scl[j];

    // fused LoRA: acc += T_tile @ loraB_tile^T (K=16 zero-padded to 32)
    bf16x8 zf = {};
    bf16x8 a2[4], b2[4];
#pragma unroll
    for (int i = 0; i < 4; i++)
        a2[i] = (lk < 2) ? *(const bf16x8*)(T + (size_t)(bm + wm + i * 16 + lrow) * RANK + lk * 8)
                         : zf;
#pragma unroll
    for (int j = 0; j < 4; j++)
        b2[j] = (lk < 2) ? *(const bf16x8*)(loraB + (size_t)(bn + wn + j * 16 + lrow) * RANK + lk * 8)
                         : zf;
#pragma unroll
    for (int i = 0; i < 4; i++)
#pragma unroll
        for (int j = 0; j < 4; j++)
            acc[i][j] = MFMA_16x16x32(a2[i], b2[j], acc[i][j]);

    // store f32: C/D layout col=lane&15, row=(lane>>4)*4+reg
#pragma unroll
    for (int i = 0; i < 4; i++)
#pragma unroll
        for (int j = 0; j < 4; j++)
#pragma unroll
            for (int r = 0; r < 4; r++) {
                int gm = bm + wm + i * 16 + lk * 4 + r;
                int gn = bn + wn + j * 16 + lrow;
                out[(size_t)gm * N_TOT + gn] = acc[i][j][r];
            }
}

// ---------------------------------------------------------------------------
// Fallback (no workspace needed): naive fp32, correctness insurance only.
// Grid (M/64, N/64), 256 threads. Computes local T tile, then outputs.
// ---------------------------------------------------------------------------
__global__ __launch_bounds__(256) void fallback_kernel(
    const float* __restrict__ X, const float* __restrict__ W,
    const float* __restrict__ scale, const float* __restrict__ lA,
    const float* __restrict__ lB, float* __restrict__ out)
{
    __shared__ float Tloc[64 * 16];
    const int bm = blockIdx.x * 64, bn = blockIdx.y * 64;

    for (int p = threadIdx.x; p < 1024; p += 256) {
        int m = p >> 4, r = p & 15;
        const float* xr = X + (size_t)(bm + m) * K_TOT;
        const float* ar = lA + (size_t)r * K_TOT;
        float s = 0.f;
        for (int k = 0; k < K_TOT; k++) s += xr[k] * ar[k];
        Tloc[m * 16 + r] = SCALING * s;
    }
    __syncthreads();

    const int m  = threadIdx.x >> 2;
    const int nq = threadIdx.x & 3;
    const float* xr = X + (size_t)(bm + m) * K_TOT;
    for (int jj = 0; jj < 16; jj++) {
        int n = nq * 16 + jj;
        const float* wr = W + (size_t)(bn + n) * K_TOT;
        float s = 0.f;
        for (int k = 0; k < K_TOT; k++) s += xr[k] * wr[k];
        float l = 0.f;
        for (int r = 0; r < 16; r++) l += Tloc[m * 16 + r] * lB[(size_t)(bn + n) * RANK + r];
        out[(size_t)(bm + m) * N_TOT + (bn + n)] = s * scale[bn + n] + l;
    }
}

// ---------------------------------------------------------------------------
extern "C" void kernel_launch(void* const* d_in, const int* in_sizes, int n_in,
                              void* d_out, int out_size, void* d_ws, size_t ws_size,
                              hipStream_t stream) {
    (void)in_sizes; (void)n_in; (void)out_size;
    const float* x      = (const float*)d_in[0];  // [8192][4096]
    const float* signs  = (const float*)d_in[1];  // [4096][4096]
    const float* scale  = (const float*)d_in[2];  // [4096]
    const float* lora_A = (const float*)d_in[3];  // [16][4096]
    const float* lora_B = (const float*)d_in[4];  // [4096][16]
    float* out = (float*)d_out;

    // ws layout (bytes):
    const size_t XB_OFF = 0;                         // 8192*4096*2 = 67108864
    const size_t WB_OFF = 67108864;                  // 4096*4096*2 = 33554432
    const size_t AB_OFF = 100663296;                 // 16*4096*2   = 131072
    const size_t BB_OFF = 100794368;                 // 4096*16*2   = 131072
    const size_t T_OFF  = 100925440;                 // 8192*16*2   = 262144
    const size_t NEEDED = 101187584;

    if (ws_size >= NEEDED) {
        __hip_bfloat16* Xb = (__hip_bfloat16*)((char*)d_ws + XB_OFF);
        __hip_bfloat16* Wb = (__hip_bfloat16*)((char*)d_ws + WB_OFF);
        __hip_bfloat16* Ab = (__hip_bfloat16*)((char*)d_ws + AB_OFF);
        __hip_bfloat16* Bb = (__hip_bfloat16*)((char*)d_ws + BB_OFF);
        __hip_bfloat16* T  = (__hip_bfloat16*)((char*)d_ws + T_OFF);

        cvt_f32_to_bf16<<<M_TOT * K_TOT / 2048, 256, 0, stream>>>(x, Xb, M_TOT * K_TOT);
        cvt_f32_to_bf16<<<N_TOT * K_TOT / 2048, 256, 0, stream>>>(signs, Wb, N_TOT * K_TOT);
        cvt_f32_to_bf16<<<RANK * K_TOT / 2048, 256, 0, stream>>>(lora_A, Ab, RANK * K_TOT);
        cvt_f32_to_bf16<<<N_TOT * RANK / 2048, 256, 0, stream>>>(lora_B, Bb, N_TOT * RANK);

        lora_t_kernel<<<128, 256, 0, stream>>>(Xb, Ab, T);

        dim3 grid(M_TOT / BM, N_TOT / BN);
        gemm_lora_kernel<<<grid, 256, 0, stream>>>(Xb, Wb, scale, Bb, T, out);
    } else {
        dim3 grid(M_TOT / 64, N_TOT / 64);
        fallback_kernel<<<grid, 256, 0, stream>>>(x, signs, scale, lora_A, lora_B, out);
    }
}

// Round 3
// 631.188 us; speedup vs baseline: 1.0274x; 1.0274x over previous
//
#include <hip/hip_runtime.h>
#include <hip/hip_bf16.h>
#include <stdint.h>
#include <stddef.h>

// LoRALinear: M=B*S=8192, K=IN_F=4096, N=OUT_F=4096, RANK=16, SCALING=2
// Inputs/output fp32; compute via bf16 MFMA (absmax 0.125 vs thr 0.675 @ R2).
#define M_TOT 8192
#define K_TOT 4096
#define N_TOT 4096
#define RANK  16
#define SCALING 2.0f

typedef short bf16x8 __attribute__((ext_vector_type(8)));
typedef float f32x4  __attribute__((ext_vector_type(4)));

#define MFMA_16x16x32(a, b, c) __builtin_amdgcn_mfma_f32_16x16x32_bf16((a), (b), (c), 0, 0, 0)

__device__ __forceinline__ void async_copy16(void* lds, const void* g) {
    __builtin_amdgcn_global_load_lds(
        (const __attribute__((address_space(1))) uint32_t*)g,
        (__attribute__((address_space(3))) uint32_t*)lds,
        16, 0, 0);
}

// ---------------------------------------------------------------------------
// One-shot conversion of all four fp32 inputs to bf16, grid-stride over a
// virtual chunk space (1 chunk = 8 elements, float4 x2 -> bf16x8).
// ---------------------------------------------------------------------------
#define NXC (M_TOT * K_TOT / 8)          // 4194304 chunks
#define NWC (N_TOT * K_TOT / 8)          // 2097152
#define NAC (RANK * K_TOT / 8)           // 8192
#define NBC (N_TOT * RANK / 8)           // 8192
#define NTOTC (NXC + NWC + NAC + NBC)    // 6307840

__global__ __launch_bounds__(256) void cvt_all_kernel(
    const float* __restrict__ x, const float* __restrict__ w,
    const float* __restrict__ a, const float* __restrict__ b,
    __hip_bfloat16* __restrict__ xb, __hip_bfloat16* __restrict__ wb,
    __hip_bfloat16* __restrict__ ab, __hip_bfloat16* __restrict__ bb)
{
    for (int c = blockIdx.x * 256 + threadIdx.x; c < NTOTC; c += gridDim.x * 256) {
        const float* s; __hip_bfloat16* d; int off;
        if (c < NXC)                  { s = x; d = xb; off = c; }
        else if (c < NXC + NWC)       { s = w; d = wb; off = c - NXC; }
        else if (c < NXC + NWC + NAC) { s = a; d = ab; off = c - NXC - NWC; }
        else                          { s = b; d = bb; off = c - NXC - NWC - NAC; }
        size_t i = (size_t)off * 8;
        float4 p = *(const float4*)(s + i);
        float4 q = *(const float4*)(s + i + 4);
        union { bf16x8 v; __hip_bfloat16 h[8]; } u;
        u.h[0] = __float2bfloat16(p.x); u.h[1] = __float2bfloat16(p.y);
        u.h[2] = __float2bfloat16(p.z); u.h[3] = __float2bfloat16(p.w);
        u.h[4] = __float2bfloat16(q.x); u.h[5] = __float2bfloat16(q.y);
        u.h[6] = __float2bfloat16(q.z); u.h[7] = __float2bfloat16(q.w);
        *(bf16x8*)(d + i) = u.v;
    }
}

// ---------------------------------------------------------------------------
// T[m][r] = SCALING * sum_k X[m][k]*loraA[r][k]
// 512 blocks (16 rows each); 4 waves K-split (1024 each); LDS reduce.
// ---------------------------------------------------------------------------
__global__ __launch_bounds__(256) void lora_t_kernel(
    const __hip_bfloat16* __restrict__ X,      // [M][K] bf16
    const __hip_bfloat16* __restrict__ loraA,  // [RANK][K] bf16
    __hip_bfloat16* __restrict__ T)            // [M][RANK] bf16
{
    __shared__ float red[4][256];
    const int lane = threadIdx.x & 63;
    const int wid  = threadIdx.x >> 6;
    const int m0   = blockIdx.x * 16;
    const int lrow = lane & 15;
    const int lk   = lane >> 4;
    const int kofs = wid * (K_TOT / 4);

    f32x4 acc = {};
    const __hip_bfloat16* xp = X + (size_t)(m0 + lrow) * K_TOT + kofs + lk * 8;
    const __hip_bfloat16* ap = loraA + (size_t)lrow * K_TOT + kofs + lk * 8;

#pragma unroll 4
    for (int k0 = 0; k0 < K_TOT / 4; k0 += 32) {
        bf16x8 av = *(const bf16x8*)xp;
        bf16x8 bv = *(const bf16x8*)ap;
        xp += 32; ap += 32;
        acc = MFMA_16x16x32(av, bv, acc);
    }
    // C/D layout: col(rank)=lane&15, row=(lane>>4)*4+r
#pragma unroll
    for (int r = 0; r < 4; r++)
        red[wid][(lk * 4 + r) * 16 + lrow] = acc[r];
    __syncthreads();

    const int t = threadIdx.x;   // t = m*16 + r over the 16x16 tile
    float s = red[0][t] + red[1][t] + red[2][t] + red[3][t];
    T[(size_t)(m0 + (t >> 4)) * RANK + (t & 15)] = __float2bfloat16(SCALING * s);
}

// ---------------------------------------------------------------------------
// Main GEMM (unchanged from R2 — at the m97-structure plateau, 750 TF):
// out[m][n] = (sum_k X[m][k]*W[n][k])*scale[n] + sum_r T[m][r]*loraB[n][r]
// ---------------------------------------------------------------------------
#define BM 128
#define BN 128
#define BK 32

__global__ __launch_bounds__(256) void gemm_lora_kernel(
    const __hip_bfloat16* __restrict__ X,
    const __hip_bfloat16* __restrict__ W,
    const float* __restrict__ scale,
    const __hip_bfloat16* __restrict__ loraB,
    const __hip_bfloat16* __restrict__ T,
    float* __restrict__ out)
{
    __shared__ __align__(16) __hip_bfloat16 As[BM * BK];
    __shared__ __align__(16) __hip_bfloat16 Bs[BN * BK];

    const int tid  = threadIdx.x;
    const int lane = tid & 63;
    const int wid  = tid >> 6;
    const int wm   = (wid & 1) * 64;
    const int wn   = (wid >> 1) * 64;
    const int bm   = blockIdx.x * BM;
    const int bn   = blockIdx.y * BN;

    const int lrow = lane & 15;
    const int lk   = lane >> 4;

    f32x4 acc[4][4] = {};

    const int s0 = tid, s1 = tid + 256;
    const int ar0 = s0 >> 2, ac0 = s0 & 3;
    const int ar1 = s1 >> 2, ac1 = s1 & 3;

    const __hip_bfloat16* xg0 = X + (size_t)(bm + ar0) * K_TOT + ac0 * 8;
    const __hip_bfloat16* xg1 = X + (size_t)(bm + ar1) * K_TOT + ac1 * 8;
    const __hip_bfloat16* wg0 = W + (size_t)(bn + ar0) * K_TOT + ac0 * 8;
    const __hip_bfloat16* wg1 = W + (size_t)(bn + ar1) * K_TOT + ac1 * 8;

    for (int k0 = 0; k0 < K_TOT; k0 += BK) {
        async_copy16(As + s0 * 8, xg0);
        async_copy16(As + s1 * 8, xg1);
        async_copy16(Bs + s0 * 8, wg0);
        async_copy16(Bs + s1 * 8, wg1);
        xg0 += BK; xg1 += BK; wg0 += BK; wg1 += BK;
        __syncthreads();

        bf16x8 af[4], bfr[4];
#pragma unroll
        for (int i = 0; i < 4; i++) {
            af[i]  = *(const bf16x8*)(As + (wm + i * 16 + lrow) * BK + lk * 8);
            bfr[i] = *(const bf16x8*)(Bs + (wn + i * 16 + lrow) * BK + lk * 8);
        }
#pragma unroll
        for (int i = 0; i < 4; i++)
#pragma unroll
            for (int j = 0; j < 4; j++)
                acc[i][j] = MFMA_16x16x32(af[i], bfr[j], acc[i][j]);
        __syncthreads();
    }

    float scl[4];
#pragma unroll
    for (int j = 0; j < 4; j++)
        scl[j] = scale[bn + wn + j * 16 + lrow];
#pragma unroll
    for (int i = 0; i < 4; i++)
#pragma unroll
        for (int j = 0; j < 4; j++)
#pragma unroll
            for (int r = 0; r < 4; r++)
                acc[i][j][r] *= scl[j];

    // fused LoRA epilogue: K=16 zero-padded to 32
    bf16x8 zf = {};
    bf16x8 a2[4], b2[4];
#pragma unroll
    for (int i = 0; i < 4; i++)
        a2[i] = (lk < 2) ? *(const bf16x8*)(T + (size_t)(bm + wm + i * 16 + lrow) * RANK + lk * 8)
                         : zf;
#pragma unroll
    for (int j = 0; j < 4; j++)
        b2[j] = (lk < 2) ? *(const bf16x8*)(loraB + (size_t)(bn + wn + j * 16 + lrow) * RANK + lk * 8)
                         : zf;
#pragma unroll
    for (int i = 0; i < 4; i++)
#pragma unroll
        for (int j = 0; j < 4; j++)
            acc[i][j] = MFMA_16x16x32(a2[i], b2[j], acc[i][j]);

#pragma unroll
    for (int i = 0; i < 4; i++)
#pragma unroll
        for (int j = 0; j < 4; j++)
#pragma unroll
            for (int r = 0; r < 4; r++) {
                int gm = bm + wm + i * 16 + lk * 4 + r;
                int gn = bn + wn + j * 16 + lrow;
                out[(size_t)gm * N_TOT + gn] = acc[i][j][r];
            }
}

// ---------------------------------------------------------------------------
// Fallback (ws too small): naive fp32 correctness insurance.
// ---------------------------------------------------------------------------
__global__ __launch_bounds__(256) void fallback_kernel(
    const float* __restrict__ X, const float* __restrict__ W,
    const float* __restrict__ scale, const float* __restrict__ lA,
    const float* __restrict__ lB, float* __restrict__ out)
{
    __shared__ float Tloc[64 * 16];
    const int bm = blockIdx.x * 64, bn = blockIdx.y * 64;

    for (int p = threadIdx.x; p < 1024; p += 256) {
        int m = p >> 4, r = p & 15;
        const float* xr = X + (size_t)(bm + m) * K_TOT;
        const float* ar = lA + (size_t)r * K_TOT;
        float s = 0.f;
        for (int k = 0; k < K_TOT; k++) s += xr[k] * ar[k];
        Tloc[m * 16 + r] = SCALING * s;
    }
    __syncthreads();

    const int m  = threadIdx.x >> 2;
    const int nq = threadIdx.x & 3;
    const float* xr = X + (size_t)(bm + m) * K_TOT;
    for (int jj = 0; jj < 16; jj++) {
        int n = nq * 16 + jj;
        const float* wr = W + (size_t)(bn + n) * K_TOT;
        float s = 0.f;
        for (int k = 0; k < K_TOT; k++) s += xr[k] * wr[k];
        float l = 0.f;
        for (int r = 0; r < 16; r++) l += Tloc[m * 16 + r] * lB[(size_t)(bn + n) * RANK + r];
        out[(size_t)(bm + m) * N_TOT + (bn + n)] = s * scale[bn + n] + l;
    }
}

// ---------------------------------------------------------------------------
extern "C" void kernel_launch(void* const* d_in, const int* in_sizes, int n_in,
                              void* d_out, int out_size, void* d_ws, size_t ws_size,
                              hipStream_t stream) {
    (void)in_sizes; (void)n_in; (void)out_size;
    const float* x      = (const float*)d_in[0];
    const float* signs  = (const float*)d_in[1];
    const float* scale  = (const float*)d_in[2];
    const float* lora_A = (const float*)d_in[3];
    const float* lora_B = (const float*)d_in[4];
    float* out = (float*)d_out;

    const size_t XB_OFF = 0;                         // 67108864 B
    const size_t WB_OFF = 67108864;                  // 33554432 B
    const size_t AB_OFF = 100663296;                 // 131072 B
    const size_t BB_OFF = 100794368;                 // 131072 B
    const size_t T_OFF  = 100925440;                 // 262144 B
    const size_t NEEDED = 101187584;

    if (ws_size >= NEEDED) {
        __hip_bfloat16* Xb = (__hip_bfloat16*)((char*)d_ws + XB_OFF);
        __hip_bfloat16* Wb = (__hip_bfloat16*)((char*)d_ws + WB_OFF);
        __hip_bfloat16* Ab = (__hip_bfloat16*)((char*)d_ws + AB_OFF);
        __hip_bfloat16* Bb = (__hip_bfloat16*)((char*)d_ws + BB_OFF);
        __hip_bfloat16* T  = (__hip_bfloat16*)((char*)d_ws + T_OFF);

        cvt_all_kernel<<<4096, 256, 0, stream>>>(x, signs, lora_A, lora_B, Xb, Wb, Ab, Bb);
        lora_t_kernel<<<M_TOT / 16, 256, 0, stream>>>(Xb, Ab, T);
        dim3 grid(M_TOT / BM, N_TOT / BN);
        gemm_lora_kernel<<<grid, 256, 0, stream>>>(Xb, Wb, scale, Bb, T, out);
    } else {
        dim3 grid(M_TOT / 64, N_TOT / 64);
        fallback_kernel<<<grid, 256, 0, stream>>>(x, signs, scale, lora_A, lora_B, out);
    }
}